// Round 2
// baseline (254.904 us; speedup 1.0000x reference)
//
#include <hip/hip_runtime.h>
#include <hip/hip_bf16.h>
#include <stdint.h>

#define G_ 4
#define N_ 4096
#define D_ 1024
#define KT_ (D_ / 64)   // 16 K-tiles of BK=64
#define MAX_LOGIT_SCALE_F 4.605170185988091f

typedef __bf16 bf16;
typedef __bf16 bf16x8 __attribute__((ext_vector_type(8)));
typedef __bf16 bf16x4 __attribute__((ext_vector_type(4)));
typedef float f32x4 __attribute__((ext_vector_type(4)));

// ---------------------------------------------------------------------------
// Mask dtype detection (reference dtype bool; harness may store bytes or i32).
// ---------------------------------------------------------------------------
__device__ inline bool mask_is_bytes(const void* masks) {
  const unsigned char* b = (const unsigned char*)masks;
  return (b[1] | b[2] | b[3]) != 0;
}
__device__ inline float mask_val(const void* masks, int idx, bool as_bytes) {
  if (as_bytes) return ((const unsigned char*)masks)[idx] ? 1.0f : 0.0f;
  return ((const int*)masks)[idx] ? 1.0f : 0.0f;
}

// ---------------------------------------------------------------------------
// Kernel 1: L2-normalize rows, emit bf16. One 256-thread block per 1024-f32
// row; float4 loads. ~BW-bound (201 MB total traffic).
// ---------------------------------------------------------------------------
__global__ __launch_bounds__(256) void norm_kernel(
    const float* __restrict__ merged, const float* __restrict__ orig,
    bf16* __restrict__ z) {
  const int row = blockIdx.x;
  const int GN = G_ * N_;
  const float* src = (row < GN) ? (merged + (size_t)row * D_)
                                : (orig + (size_t)(row - GN) * D_);
  const int tid = threadIdx.x;
  float4 v = reinterpret_cast<const float4*>(src)[tid];
  float ss = v.x * v.x + v.y * v.y + v.z * v.z + v.w * v.w;
#pragma unroll
  for (int off = 32; off; off >>= 1) ss += __shfl_down(ss, off, 64);
  __shared__ float wsum[4];
  if ((tid & 63) == 0) wsum[tid >> 6] = ss;
  __syncthreads();
  const float tot = wsum[0] + wsum[1] + wsum[2] + wsum[3];
  const float inv = 1.0f / fmaxf(sqrtf(tot), 1e-12f);
  bf16x4 o;
  o[0] = (bf16)(v.x * inv);
  o[1] = (bf16)(v.y * inv);
  o[2] = (bf16)(v.z * inv);
  o[3] = (bf16)(v.w * inv);
  *reinterpret_cast<bf16x4*>(z + (size_t)row * D_ + tid * 4) = o;
}

// ---------------------------------------------------------------------------
// Kernel 2: 256x256-tile bf16 GEMM (z1 . z2^T per group) + fused SigLIP loss.
// BK=64, 8 waves (2M x 4N, 128x64 output each), 16x16x32 MFMA.
// T2: st-swizzle via inverse-swizzled global source (linear global_load_lds
//     dest) + swizzled ds_read — byte ^= (row&7)<<4 within each 128-B row.
// T3/T4: raw s_barrier + counted s_waitcnt vmcnt(8); 2-tile-deep prefetch;
//     stage of buf[cur] issued only AFTER the barrier ending its reads.
// T5: setprio(1) around each 16-MFMA quadrant.
// One float partial per block (deterministic; no atomics).
// ---------------------------------------------------------------------------
__global__ __launch_bounds__(512, 2) void gemm_loss_kernel(
    const bf16* __restrict__ z1, const bf16* __restrict__ z2,
    const void* __restrict__ masks,
    const float* __restrict__ p_ls, const float* __restrict__ p_lb,
    float* __restrict__ partial) {
  // LDS: [buf][A 256x64 | B 256x64] bf16 = 2*2*16384*2 B = 128 KiB
  __shared__ bf16 sh[2 * 32768];

  const int g  = blockIdx.z;
  const int tm = blockIdx.y * 256;
  const int tn = blockIdx.x * 256;
  const bf16* Abase = z1 + ((size_t)g * N_ + tm) * D_;
  const bf16* Bbase = z2 + ((size_t)g * N_ + tn) * D_;

  const int tid  = threadIdx.x;
  const int wave = tid >> 6;
  const int lane = tid & 63;
  const int wm = wave >> 2;   // 0..1 -> row offset wm*128
  const int wn = wave & 3;    // 0..3 -> col offset wn*64

  // staging indices: op = 64 rows x 64 cols (8 KB); thread -> row tid/8,
  // 16-B granule (tid&7); source col pre-XOR'd so linear LDS == swizzled.
  const int sr  = tid >> 3;                          // 0..63
  const int sce = ((tid & 7) * 8) ^ ((sr & 7) * 8);  // swizzled elem col

  f32x4 acc[8][4] = {};

  auto stage = [&](int buf, int kt) {
    bf16* sA = sh + buf * 32768;
    bf16* sB = sA + 16384;
    const int k0 = kt * 64;
#pragma unroll
    for (int o = 0; o < 4; ++o) {
      const bf16* srcA = Abase + (size_t)(o * 64 + sr) * D_ + (k0 + sce);
      __builtin_amdgcn_global_load_lds(
          (const __attribute__((address_space(1))) void*)srcA,
          (__attribute__((address_space(3))) void*)(sA + o * 4096 + wave * 512),
          16, 0, 0);
      const bf16* srcB = Bbase + (size_t)(o * 64 + sr) * D_ + (k0 + sce);
      __builtin_amdgcn_global_load_lds(
          (const __attribute__((address_space(1))) void*)srcB,
          (__attribute__((address_space(3))) void*)(sB + o * 4096 + wave * 512),
          16, 0, 0);
    }
  };

  const int rlo   = lane & 15;
  const int cbase = (lane >> 4) * 16;  // byte col of this lane's 16-B frag

  auto read_a = [&](const bf16* sA, int fm, int ks) -> bf16x8 {
    const int row = wm * 128 + fm * 16 + rlo;
    const int cb = (cbase + ks * 64) ^ ((row & 7) << 4);
    return *reinterpret_cast<const bf16x8*>(sA + row * 64 + (cb >> 1));
  };
  auto read_b = [&](const bf16* sB, int fn, int ks) -> bf16x8 {
    const int row = wn * 64 + fn * 16 + rlo;
    const int cb = (cbase + ks * 64) ^ ((row & 7) << 4);
    return *reinterpret_cast<const bf16x8*>(sB + row * 64 + (cb >> 1));
  };

  // prologue: 2 tiles in flight; wait own first-8 ops (tile 0), sync.
  stage(0, 0);
  stage(1, 1);
  asm volatile("s_waitcnt vmcnt(8)" ::: "memory");
  __builtin_amdgcn_sched_barrier(0);
  __builtin_amdgcn_s_barrier();
  __builtin_amdgcn_sched_barrier(0);

  for (int kt = 0; kt < KT_; ++kt) {
    const int buf = kt & 1;
    const bf16* sA = sh + buf * 32768;
    const bf16* sB = sA + 16384;

    bf16x8 aLo[4][2], aHi[4][2], bLo[2][2], bHi[2][2];

    // phase 1: m0-3 x n0-1
#pragma unroll
    for (int i = 0; i < 4; ++i) {
      aLo[i][0] = read_a(sA, i, 0);
      aLo[i][1] = read_a(sA, i, 1);
    }
#pragma unroll
    for (int j = 0; j < 2; ++j) {
      bLo[j][0] = read_b(sB, j, 0);
      bLo[j][1] = read_b(sB, j, 1);
    }
    __builtin_amdgcn_s_setprio(1);
#pragma unroll
    for (int i = 0; i < 4; ++i)
#pragma unroll
      for (int j = 0; j < 2; ++j)
#pragma unroll
        for (int ks = 0; ks < 2; ++ks)
          acc[i][j] = __builtin_amdgcn_mfma_f32_16x16x32_bf16(
              aLo[i][ks], bLo[j][ks], acc[i][j], 0, 0, 0);
    __builtin_amdgcn_s_setprio(0);

    // phase 2: m0-3 x n2-3
#pragma unroll
    for (int j = 0; j < 2; ++j) {
      bHi[j][0] = read_b(sB, j + 2, 0);
      bHi[j][1] = read_b(sB, j + 2, 1);
    }
    __builtin_amdgcn_s_setprio(1);
#pragma unroll
    for (int i = 0; i < 4; ++i)
#pragma unroll
      for (int j = 0; j < 2; ++j)
#pragma unroll
        for (int ks = 0; ks < 2; ++ks)
          acc[i][j + 2] = __builtin_amdgcn_mfma_f32_16x16x32_bf16(
              aLo[i][ks], bHi[j][ks], acc[i][j + 2], 0, 0, 0);
    __builtin_amdgcn_s_setprio(0);

    // phase 3: m4-7 x n2-3
#pragma unroll
    for (int i = 0; i < 4; ++i) {
      aHi[i][0] = read_a(sA, i + 4, 0);
      aHi[i][1] = read_a(sA, i + 4, 1);
    }
    __builtin_amdgcn_s_setprio(1);
#pragma unroll
    for (int i = 0; i < 4; ++i)
#pragma unroll
      for (int j = 0; j < 2; ++j)
#pragma unroll
        for (int ks = 0; ks < 2; ++ks)
          acc[i + 4][j + 2] = __builtin_amdgcn_mfma_f32_16x16x32_bf16(
              aHi[i][ks], bHi[j][ks], acc[i + 4][j + 2], 0, 0, 0);
    __builtin_amdgcn_s_setprio(0);

    // phase 4: m4-7 x n0-1 (bLo still live)
    __builtin_amdgcn_s_setprio(1);
#pragma unroll
    for (int i = 0; i < 4; ++i)
#pragma unroll
      for (int j = 0; j < 2; ++j)
#pragma unroll
        for (int ks = 0; ks < 2; ++ks)
          acc[i + 4][j] = __builtin_amdgcn_mfma_f32_16x16x32_bf16(
              aHi[i][ks], bLo[j][ks], acc[i + 4][j], 0, 0, 0);
    __builtin_amdgcn_s_setprio(0);

    // all waves done READING buf -> safe to overwrite it
    __builtin_amdgcn_sched_barrier(0);
    __builtin_amdgcn_s_barrier();
    __builtin_amdgcn_sched_barrier(0);

    if (kt < KT_ - 2) {
      stage(buf, kt + 2);
      // wait tile kt+1 (8 oldest ops) landed; kt+2's 8 stay in flight
      asm volatile("s_waitcnt vmcnt(8)" ::: "memory");
    } else {
      asm volatile("s_waitcnt vmcnt(0)" ::: "memory");
    }
    __builtin_amdgcn_sched_barrier(0);
    __builtin_amdgcn_s_barrier();
    __builtin_amdgcn_sched_barrier(0);
  }

  // ---- fused loss epilogue ----
  const float scale = expf(fminf(p_ls[0], MAX_LOGIT_SCALE_F));
  const float lbias = p_lb[0];
  const bool as_bytes = mask_is_bytes(masks);
  const int mbase = g * N_;

  // C/D layout (m89): col = lane&15, row = (lane>>4)*4 + reg
  const int row0 = tm + wm * 128 + ((lane >> 4) << 2);
  const int col0 = tn + wn * 64 + (lane & 15);

  float lsum = 0.0f;
#pragma unroll
  for (int fn = 0; fn < 4; ++fn) {
    const int c = col0 + fn * 16;
    const float mC = mask_val(masks, mbase + c, as_bytes);
#pragma unroll
    for (int fm = 0; fm < 8; ++fm) {
#pragma unroll
      for (int j = 0; j < 4; ++j) {
        const int r = row0 + fm * 16 + j;
        const float mR = mask_val(masks, mbase + r, as_bytes);
        const float v = acc[fm][fn][j] * scale + lbias;  // logit
        const float u = (r == c) ? -v : v;               // -label*logit
        const float loss = fmaxf(u, 0.0f) + __logf(1.0f + __expf(-fabsf(u)));
        lsum += mR * mC * loss;
      }
    }
  }

#pragma unroll
  for (int off = 32; off; off >>= 1) lsum += __shfl_down(lsum, off, 64);
  float* red = (float*)sh;  // reads long done (final barrier passed)
  if (lane == 0) red[wave] = lsum;
  __syncthreads();
  if (tid == 0) {
    float s = 0.0f;
#pragma unroll
    for (int w = 0; w < 8; ++w) s += red[w];
    partial[((size_t)g * 16 + blockIdx.y) * 16 + blockIdx.x] = s;
  }
}

// ---------------------------------------------------------------------------
// Kernel 3: n_sel per group + masked mean over valid groups -> scalar.
// ---------------------------------------------------------------------------
__global__ __launch_bounds__(256) void finalize_kernel(
    const void* __restrict__ masks, const float* __restrict__ partial,
    float* __restrict__ out) {
  const int tid = threadIdx.x;
  const bool as_bytes = mask_is_bytes(masks);
  __shared__ float redc[G_][4];
  __shared__ float redp[G_][4];
  for (int g = 0; g < G_; ++g) {
    float cnt = 0.0f, ps = 0.0f;
    for (int i = tid; i < N_; i += 256) cnt += mask_val(masks, g * N_ + i, as_bytes);
    for (int i = tid; i < 256; i += 256) ps += partial[g * 256 + i];
#pragma unroll
    for (int off = 32; off; off >>= 1) {
      cnt += __shfl_down(cnt, off, 64);
      ps  += __shfl_down(ps,  off, 64);
    }
    if ((tid & 63) == 0) { redc[g][tid >> 6] = cnt; redp[g][tid >> 6] = ps; }
  }
  __syncthreads();
  if (tid == 0) {
    float tot = 0.0f, nv = 0.0f;
    for (int g = 0; g < G_; ++g) {
      const float ns = redc[g][0] + redc[g][1] + redc[g][2] + redc[g][3];
      const float pg = redp[g][0] + redp[g][1] + redp[g][2] + redp[g][3];
      if (ns > 0.0f) { tot += pg / fmaxf(ns * ns, 1.0f); nv += 1.0f; }
    }
    out[0] = tot / fmaxf(nv, 1.0f);
  }
}

// ---------------------------------------------------------------------------
extern "C" void kernel_launch(void* const* d_in, const int* in_sizes, int n_in,
                              void* d_out, int out_size, void* d_ws, size_t ws_size,
                              hipStream_t stream) {
  const float* merged = (const float*)d_in[0];
  const float* orig   = (const float*)d_in[1];
  const void*  masks  = (const void*)d_in[2];
  const float* ls     = (const float*)d_in[3];
  const float* lb     = (const float*)d_in[4];
  float* out = (float*)d_out;

  // ws: z1 [G*N*D bf16] | z2 [G*N*D bf16] | partial [G*256 f32]
  bf16* z1 = (bf16*)d_ws;
  bf16* z2 = z1 + (size_t)G_ * N_ * D_;
  float* partial = (float*)((char*)d_ws + (size_t)2 * G_ * N_ * D_ * sizeof(bf16));

  norm_kernel<<<2 * G_ * N_, 256, 0, stream>>>(merged, orig, z1);
  gemm_loss_kernel<<<dim3(16, 16, G_), 512, 0, stream>>>(z1, z2, masks, ls, lb,
                                                         partial);
  finalize_kernel<<<1, 256, 0, stream>>>(masks, partial, out);
}